// Round 4
// baseline (363.858 us; speedup 1.0000x reference)
//
#include <hip/hip_runtime.h>
#include <stdint.h>

#define T_SEQ 2048
#define B_SZ 2
#define N_HEAD 16
#define D_HEAD 128
#define C_DIM 2048
#define M_ROWS (B_SZ*T_SEQ)   // 4096
#define N_BH (B_SZ*N_HEAD)    // 32

typedef _Float16 f16;
typedef f16 f16x8 __attribute__((ext_vector_type(8)));
typedef f16 f16x4 __attribute__((ext_vector_type(4)));
typedef float f32x4 __attribute__((ext_vector_type(4)));

#define MFMA_F16(a,b,c) __builtin_amdgcn_mfma_f32_16x16x32_f16(a,b,c,0,0,0)

#define BAR_LGKM() do { asm volatile("s_waitcnt lgkmcnt(0)" ::: "memory"); \
                        __builtin_amdgcn_s_barrier(); } while (0)
#define BAR_ALL()  do { asm volatile("s_waitcnt vmcnt(0) lgkmcnt(0)" ::: "memory"); \
                        __builtin_amdgcn_s_barrier(); } while (0)

// async global->LDS, 16B per lane; LDS dest is wave-uniform base + lane*16
__device__ __forceinline__ void gl_lds16(const void* g, void* l) {
  __builtin_amdgcn_global_load_lds(
      (const __attribute__((address_space(1))) unsigned int*)g,
      (__attribute__((address_space(3))) unsigned int*)l, 16, 0, 0);
}

// ---------------- prep: W -> Wb (fp16) and Wtb (fp16, transposed) ----------
__global__ void k_prep_w(const float* __restrict__ W, f16* __restrict__ Wb,
                         f16* __restrict__ Wtb) {
  __shared__ float tile[64][65];
  const int bx = blockIdx.x * 64;   // col base
  const int by = blockIdx.y * 64;   // row base
  const int t = threadIdx.x;
  const int tc = t & 63, tr4 = t >> 6;
  for (int rr = tr4; rr < 64; rr += 4) {
    float v = W[(size_t)(by + rr) * C_DIM + bx + tc];
    tile[rr][tc] = v;
    Wb[(size_t)(by + rr) * C_DIM + bx + tc] = (f16)v;
  }
  __syncthreads();
  for (int rr = tr4; rr < 64; rr += 4) {
    // Wtb[n][k] = W[k][n]
    Wtb[(size_t)(bx + rr) * C_DIM + by + tc] = (f16)tile[tc][rr];
  }
}

// ---------------- prep: x -> fp16 ------------------------------------------
__global__ void k_prep_x(const float* __restrict__ x, f16* __restrict__ xb) {
  int i = blockIdx.x * blockDim.x + threadIdx.x;
  const int stride = gridDim.x * blockDim.x;
  const int n4 = (M_ROWS * C_DIM) / 4;
  for (; i < n4; i += stride) {
    f32x4 v = ((const f32x4*)x)[i];
    f16x4 o; o[0]=(f16)v[0]; o[1]=(f16)v[1]; o[2]=(f16)v[2]; o[3]=(f16)v[3];
    ((f16x4*)xb)[i] = o;
  }
}

// ---------------- GEMM C[M][N] = sum_k A[m][k]*B[n][k]  (B^T layout) -------
template<typename OT>
__global__ __launch_bounds__(256, 2)
void k_gemm_bt(const f16* __restrict__ A, const f16* __restrict__ Bm,
               OT* __restrict__ C, int Nd, int Kd) {
  __shared__ __align__(16) f16 As[2][128 * 64];
  __shared__ __align__(16) f16 Bs[2][128 * 64];
  const int tid = threadIdx.x;
  const int lane = tid & 63, wid = tid >> 6;
  const int lr = lane & 15, lkg = lane >> 4;
  const int wr = wid >> 1, wc = wid & 1;
  const int tm = blockIdx.y * 128, tn = blockIdx.x * 128;

  f32x4 acc[4][4];
#pragma unroll
  for (int i = 0; i < 4; ++i)
#pragma unroll
    for (int j = 0; j < 4; ++j) acc[i][j] = (f32x4){0.f, 0.f, 0.f, 0.f};

  const int nkt = Kd >> 6;

  auto stage = [&](int buf, int kt) {
    const int k0 = kt << 6;
    for (int s = 0; s < 4; ++s) {
      const int r0 = (wid * 4 + s) * 8;
      const int r = r0 + (lane >> 3);
      const int lg = ((lane & 7) ^ (r & 7)) << 3;  // logical col (elems)
      gl_lds16(A + (size_t)(tm + r) * Kd + k0 + lg, &As[buf][r0 * 64]);
      gl_lds16(Bm + (size_t)(tn + r) * Kd + k0 + lg, &Bs[buf][r0 * 64]);
    }
  };

  stage(0, 0);
  int cur = 0;
  for (int kt = 0; kt < nkt; ++kt) {
    __syncthreads();                       // staged buf[cur] ready
    if (kt + 1 < nkt) stage(cur ^ 1, kt + 1);
#pragma unroll
    for (int kk = 0; kk < 2; ++kk) {
      f16x8 a[4], b[4];
#pragma unroll
      for (int i = 0; i < 4; ++i) {
        const int ra = wr * 64 + i * 16 + lr;
        const int ga = ((kk * 4 + lkg) ^ (ra & 7)) << 3;
        a[i] = *(const f16x8*)&As[cur][ra * 64 + ga];
        const int rb = wc * 64 + i * 16 + lr;
        const int gb = ((kk * 4 + lkg) ^ (rb & 7)) << 3;
        b[i] = *(const f16x8*)&Bs[cur][rb * 64 + gb];
      }
#pragma unroll
      for (int i = 0; i < 4; ++i)
#pragma unroll
        for (int j = 0; j < 4; ++j) acc[i][j] = MFMA_F16(a[i], b[j], acc[i][j]);
    }
    cur ^= 1;
  }
#pragma unroll
  for (int i = 0; i < 4; ++i) {
    const int row0 = tm + wr * 64 + i * 16 + lkg * 4;
#pragma unroll
    for (int j = 0; j < 4; ++j) {
      const int col = tn + wc * 64 + j * 16 + lr;
#pragma unroll
      for (int r = 0; r < 4; ++r)
        C[(size_t)(row0 + r) * Nd + col] = (OT)acc[i][j][r];
    }
  }
}

// ---------------- RMS norm: wb[B,T,H,D] -> n,m in [B,H,T,D] ---------------
__global__ __launch_bounds__(256, 4)
void k_rms(const f16* __restrict__ wb, const float* __restrict__ g1,
           const float* __restrict__ g2, f16* __restrict__ nb,
           f16* __restrict__ mb) {
  const int tid = threadIdx.x, lane = tid & 63, wid = tid >> 6;
  const int lr = lane & 15, grp = lane >> 4;
  float gs[8];
#pragma unroll
  for (int e = 0; e < 8; ++e)
    gs[e] = g1[lr * 8 + e] * g2[lr * 8 + e] * 0.08838834764831843f; // /sqrt(128)
  const int R = blockIdx.x * 16 + wid * 4 + grp;  // ((b*T+t)*H + h)
  const f16x8 w8 = *(const f16x8*)&wb[(size_t)R * 128 + lr * 8];
  float f[8];
  float ss = 0.f;
#pragma unroll
  for (int e = 0; e < 8; ++e) { f[e] = (float)w8[e]; ss += f[e] * f[e]; }
  ss += __shfl_xor(ss, 1); ss += __shfl_xor(ss, 2);
  ss += __shfl_xor(ss, 4); ss += __shfl_xor(ss, 8);
  const float scale = rsqrtf(ss * (1.f / 128.f) + 1.1920928955078125e-07f);
  const int hh = R & (N_HEAD - 1);
  const int bt = R >> 4;
  const int b = bt >> 11;
  const int t = bt & (T_SEQ - 1);
  const size_t dst = ((size_t)((b * N_HEAD + hh) * T_SEQ + t)) * 128 + lr * 8;
  f16x8 n8, m8;
#pragma unroll
  for (int e = 0; e < 8; ++e) {
    float nf = f[e] * scale;
    n8[e] = (f16)nf;
    m8[e] = (f16)(nf * gs[e]);
  }
  *(f16x8*)&nb[dst] = n8;
  *(f16x8*)&mb[dst] = m8;
}

// ---------------- transpose n[bh][t][d] -> nT[bh][d][t] --------------------
__global__ void k_tn(const f16* __restrict__ nin, f16* __restrict__ nT) {
  __shared__ __align__(16) f16 tile[64][72];
  const int t = threadIdx.x;
  const int c = t & 7, r4 = t >> 3;
  const int bh = blockIdx.z, t0 = blockIdx.x * 64, d0 = blockIdx.y * 64;
  const f16* src = nin + ((size_t)bh * T_SEQ + t0) * 128 + d0;
  for (int rr = r4; rr < 64; rr += 32)
    *(f16x8*)&tile[rr][c * 8] = *(const f16x8*)&src[(size_t)rr * 128 + c * 8];
  __syncthreads();
  f16* dst = nT + ((size_t)bh * 128 + d0) * T_SEQ + t0;
  for (int rr = r4; rr < 64; rr += 32) {
    f16x8 v;
#pragma unroll
    for (int e = 0; e < 8; ++e) v[e] = tile[c * 8 + e][rr];
    *(f16x8*)&dst[(size_t)rr * T_SEQ + c * 8] = v;
  }
}

// ---------------- stats v2: alpha_i = 1 / sum_j exp(att_ij) ---------------
__global__ __launch_bounds__(256, 2)
void k_stats(const f16* __restrict__ mIn, const f16* __restrict__ nIn,
             float* __restrict__ alpha) {
  __shared__ __align__(16) f16 Ns[2][128 * 128];   // 64KB dbuf
  __shared__ float red[256];
  const int tid = threadIdx.x, lane = tid & 63, wid = tid >> 6;
  const int lr = lane & 15, lkg = lane >> 4;
  const int wr = wid >> 1, wc = wid & 1;
  const int it = blockIdx.x, bh = blockIdx.y;
  const f16* mp = mIn + (size_t)bh * T_SEQ * 128;
  const f16* np = nIn + (size_t)bh * T_SEQ * 128;

  // A-operand fragments (M rows for this block), block-constant: 64 VGPR
  f16x8 msr[4][4];
#pragma unroll
  for (int i = 0; i < 4; ++i)
#pragma unroll
    for (int kk = 0; kk < 4; ++kk)
      msr[i][kk] = *(const f16x8*)&mp[(size_t)(it * 128 + wr * 64 + i * 16 + lr) * 128 +
                                      (kk * 4 + lkg) * 8];

  auto stageN = [&](int buf, int jt) {
#pragma unroll
    for (int s = 0; s < 8; ++s) {
      const int r0 = (wid * 8 + s) * 4;
      const int r = r0 + (lane >> 4);
      const int lg = ((lane & 15) ^ (r & 7)) << 3;
      gl_lds16(np + (size_t)(jt * 128 + r) * 128 + lg, &Ns[buf][r0 * 128]);
    }
  };

  float srun[16];
#pragma unroll
  for (int q = 0; q < 16; ++q) srun[q] = 0.f;

  stageN(0, 0);
  BAR_ALL();
  int cur = 0;
  for (int jt = 0; jt < 16; ++jt) {
    if (jt < 15) stageN(cur ^ 1, jt + 1);   // DMA overlaps QK+exp
    f32x4 acc[4][4];
#pragma unroll
    for (int i = 0; i < 4; ++i)
#pragma unroll
      for (int j = 0; j < 4; ++j) acc[i][j] = (f32x4){0.f, 0.f, 0.f, 0.f};
#pragma unroll
    for (int kk = 0; kk < 4; ++kk) {
      f16x8 b[4];
#pragma unroll
      for (int j = 0; j < 4; ++j) {
        const int rb = wc * 64 + j * 16 + lr;
        const int gb = ((kk * 4 + lkg) ^ (rb & 7)) << 3;
        b[j] = *(const f16x8*)&Ns[cur][rb * 128 + gb];
      }
#pragma unroll
      for (int i = 0; i < 4; ++i)
#pragma unroll
        for (int j = 0; j < 4; ++j)
          acc[i][j] = MFMA_F16(msr[i][kk], b[j], acc[i][j]);
    }
#pragma unroll
    for (int i = 0; i < 4; ++i)
#pragma unroll
      for (int r = 0; r < 4; ++r) {
        float s = __expf(acc[i][0][r]) + __expf(acc[i][1][r]) +
                  __expf(acc[i][2][r]) + __expf(acc[i][3][r]);
        srun[i * 4 + r] += s;
      }
    BAR_ALL();                  // staged Ns ready; all reads of cur done
    cur ^= 1;
  }
#pragma unroll
  for (int q = 0; q < 16; ++q) {
    float v = srun[q];
    v += __shfl_xor(v, 1); v += __shfl_xor(v, 2);
    v += __shfl_xor(v, 4); v += __shfl_xor(v, 8);
    srun[q] = v;
  }
  if (lr == 0) {
#pragma unroll
    for (int q = 0; q < 16; ++q) {
      const int row = wr * 64 + (q >> 2) * 16 + lkg * 4 + (q & 3);
      red[row * 2 + wc] = srun[q];
    }
  }
  __syncthreads();
  if (tid < 128) {
    const float s = red[tid * 2] + red[tid * 2 + 1];
    alpha[(size_t)bh * T_SEQ + it * 128 + tid] = 1.f / s;
  }
}

// ---------------- apply v4: v3 + ping-pong ntreg issued at step TOP --------
// LDS = Ns dbuf 32KB + Ps 16KB = 48KB; 2 barriers per j-step.
__global__ __launch_bounds__(256, 2)
void k_apply(const f16* __restrict__ mIn, const f16* __restrict__ nIn,
             const f16* __restrict__ nTIn, const float* __restrict__ alpha,
             const float* __restrict__ g3, f16* __restrict__ yb) {
  __shared__ __align__(16) f16 Ns[2][64 * 128];  // 32KB  j-rows, 128 d
  __shared__ __align__(16) f16 Ps[128 * 64];     // 16KB  i-rows, 64 j
  const int tid = threadIdx.x, lane = tid & 63, wid = tid >> 6;
  const int lr = lane & 15, lkg = lane >> 4;
  const int wj = wid >> 1;  // QK: j-half (32) | PV: d-half (64)
  const int wi = wid & 1;   // i-half (64) for both
  const int it = blockIdx.x, bh = blockIdx.y;
  const int b = bh >> 4, hh = bh & 15;
  const f16* mp = mIn + (size_t)bh * T_SEQ * 128;
  const f16* np = nIn + (size_t)bh * T_SEQ * 128;
  const f16* ntp = nTIn + (size_t)bh * 128 * T_SEQ;
  const float* al = alpha + (size_t)bh * T_SEQ;

  // QK B-operand fragments (M rows for this block), block-constant: 64 VGPR
  f16x8 msr[4][4];
#pragma unroll
  for (int ii = 0; ii < 4; ++ii)
#pragma unroll
    for (int kk = 0; kk < 4; ++kk)
      msr[ii][kk] = *(const f16x8*)&mp[(size_t)(it * 128 + wi * 64 + ii * 16 + lr) * 128 +
                                       (kk * 4 + lkg) * 8];

  auto stageN = [&](int buf, int jt) {
#pragma unroll
    for (int s = 0; s < 4; ++s) {
      const int r0 = (wid * 4 + s) * 4;         // local j row
      const int r = r0 + (lane >> 4);
      const int lg = ((lane & 15) ^ (r & 7)) << 3;
      gl_lds16(np + (size_t)(jt * 64 + r) * 128 + lg, &Ns[buf][r0 * 128]);
    }
  };

  // PV A-operand ping-pong register buffers (statically indexed via macro)
  f16x8 ntA[4][2], ntB[4][2];
#define LDNT(JT, DST) do {                                                    \
  _Pragma("unroll")                                                           \
  for (int dd_ = 0; dd_ < 4; ++dd_)                                           \
    _Pragma("unroll")                                                         \
    for (int kk_ = 0; kk_ < 2; ++kk_)                                         \
      DST[dd_][kk_] = *(const f16x8*)&ntp[(size_t)(wj * 64 + dd_ * 16 + lr) * \
                                          T_SEQ + (JT) * 64 + (kk_ * 4 + lkg) * 8]; \
} while (0)

  float ai[4];
#pragma unroll
  for (int ii = 0; ii < 4; ++ii) ai[ii] = al[it * 128 + wi * 64 + ii * 16 + lr];

  f32x4 yacc[4][4];
#pragma unroll
  for (int i = 0; i < 4; ++i)
#pragma unroll
    for (int j = 0; j < 4; ++j) yacc[i][j] = (f32x4){0.f, 0.f, 0.f, 0.f};

  stageN(0, 0);
  LDNT(0, ntA);
  BAR_ALL();
  int cur = 0;

#define STEP(JT, USE, LOAD) do {                                              \
  if ((JT) < 31) { stageN(cur ^ 1, (JT) + 1); LDNT((JT) + 1, LOAD); }         \
  float aj_[8];                                                               \
  _Pragma("unroll")                                                           \
  for (int jj_ = 0; jj_ < 2; ++jj_)                                           \
    _Pragma("unroll")                                                         \
    for (int r_ = 0; r_ < 4; ++r_)                                            \
      aj_[jj_ * 4 + r_] = al[(JT) * 64 + wj * 32 + jj_ * 16 + lkg * 4 + r_];  \
  f32x4 acc_[2][4];                                                           \
  _Pragma("unroll")                                                           \
  for (int jj_ = 0; jj_ < 2; ++jj_)                                           \
    _Pragma("unroll")                                                         \
    for (int ii_ = 0; ii_ < 4; ++ii_) acc_[jj_][ii_] = (f32x4){0.f,0.f,0.f,0.f}; \
  _Pragma("unroll")                                                           \
  for (int kk_ = 0; kk_ < 4; ++kk_) {                                         \
    f16x8 a_[2];                                                              \
    _Pragma("unroll")                                                         \
    for (int jj_ = 0; jj_ < 2; ++jj_) {                                       \
      const int jrow_ = wj * 32 + jj_ * 16 + lr;                              \
      a_[jj_] = *(const f16x8*)&Ns[cur][jrow_ * 128 +                         \
                 (((kk_ * 4 + lkg) ^ (jrow_ & 7)) << 3)];                     \
    }                                                                         \
    _Pragma("unroll")                                                         \
    for (int jj_ = 0; jj_ < 2; ++jj_)                                         \
      _Pragma("unroll")                                                       \
      for (int ii_ = 0; ii_ < 4; ++ii_)                                       \
        acc_[jj_][ii_] = MFMA_F16(a_[jj_], msr[ii_][kk_], acc_[jj_][ii_]);    \
  }                                                                           \
  _Pragma("unroll")                                                           \
  for (int jj_ = 0; jj_ < 2; ++jj_)                                           \
    _Pragma("unroll")                                                         \
    for (int ii_ = 0; ii_ < 4; ++ii_) {                                       \
      f16x4 o_;                                                               \
      _Pragma("unroll")                                                       \
      for (int r_ = 0; r_ < 4; ++r_)                                          \
        o_[r_] = (f16)(__expf(acc_[jj_][ii_][r_]) * (ai[ii_] + aj_[jj_ * 4 + r_])); \
      const int il_ = wi * 64 + ii_ * 16 + lr;                                \
      const int jl_ = wj * 32 + jj_ * 16 + lkg * 4;                           \
      *(f16x4*)&Ps[il_ * 64 + (((jl_ >> 3) ^ (il_ & 7)) << 3) + (jl_ & 7)] = o_; \
    }                                                                         \
  BAR_LGKM();                                                                 \
  _Pragma("unroll")                                                           \
  for (int kk_ = 0; kk_ < 2; ++kk_) {                                         \
    f16x8 bfr_[4];                                                            \
    _Pragma("unroll")                                                         \
    for (int ii_ = 0; ii_ < 4; ++ii_) {                                       \
      const int irow_ = wi * 64 + ii_ * 16 + lr;                              \
      bfr_[ii_] = *(const f16x8*)&Ps[irow_ * 64 +                             \
                   (((kk_ * 4 + lkg) ^ (irow_ & 7)) << 3)];                   \
    }                                                                         \
    _Pragma("unroll")                                                         \
    for (int dd_ = 0; dd_ < 4; ++dd_)                                         \
      _Pragma("unroll")                                                       \
      for (int ii_ = 0; ii_ < 4; ++ii_)                                       \
        yacc[dd_][ii_] = MFMA_F16(USE[dd_][kk_], bfr_[ii_], yacc[dd_][ii_]);  \
  }                                                                           \
  BAR_ALL();                                                                  \
  cur ^= 1;                                                                   \
} while (0)

  for (int jt = 0; jt < 32; jt += 2) {
    STEP(jt, ntA, ntB);
    STEP(jt + 1, ntB, ntA);
  }
#undef STEP
#undef LDNT

  // ---- epilogue: yb[b, t=i, hh*128+d] = yacc * g3[d] ----
#pragma unroll
  for (int dd = 0; dd < 4; ++dd) {
    const int d0 = wj * 64 + dd * 16 + lkg * 4;
    float g3v[4];
#pragma unroll
    for (int r = 0; r < 4; ++r) g3v[r] = g3[d0 + r];
#pragma unroll
    for (int ii = 0; ii < 4; ++ii) {
      const int icol = wi * 64 + ii * 16 + lr;
      const size_t base =
          ((size_t)(b * T_SEQ + it * 128 + icol)) * C_DIM + hh * 128 + d0;
      f16x4 o;
#pragma unroll
      for (int r = 0; r < 4; ++r) o[r] = (f16)(yacc[dd][ii][r] * g3v[r]);
      *(f16x4*)&yb[base] = o;
    }
  }
}

// ---------------------------------------------------------------------------
extern "C" void kernel_launch(void* const* d_in, const int* in_sizes, int n_in,
                              void* d_out, int out_size, void* d_ws,
                              size_t ws_size, hipStream_t stream) {
  const float* x = (const float*)d_in[0];
  const float* W = (const float*)d_in[1];
  const float* g1 = (const float*)d_in[2];
  const float* g2 = (const float*)d_in[3];
  const float* g3 = (const float*)d_in[4];
  float* out = (float*)d_out;
  char* ws = (char*)d_ws;

  f16* xb   = (f16*)(ws);                      // 16,777,216 B
  f16* Wb   = (f16*)(ws + 16777216);           //  8,388,608
  f16* Wtb  = (f16*)(ws + 25165824);           //  8,388,608
  f16* wb   = (f16*)(ws + 33554432);           // 16,777,216
  f16* nb   = (f16*)(ws + 50331648);           // 16,777,216
  f16* mb   = (f16*)(ws + 67108864);           // 16,777,216
  f16* nT   = (f16*)(ws + 83886080);           // 16,777,216
  f16* yb   = (f16*)(ws + 100663296);          // 16,777,216
  float* alpha = (float*)(ws + 117440512);     //    262,144  (total ~112.3 MB)

  k_prep_w<<<dim3(32, 32), 256, 0, stream>>>(W, Wb, Wtb);
  k_prep_x<<<dim3(2048), 256, 0, stream>>>(x, xb);
  k_gemm_bt<f16><<<dim3(16, 32), 256, 0, stream>>>(xb, Wb, wb, C_DIM, C_DIM);
  k_rms<<<dim3(4096), 256, 0, stream>>>(wb, g1, g2, nb, mb);
  k_tn<<<dim3(32, 2, 32), 256, 0, stream>>>(nb, nT);
  k_stats<<<dim3(16, 32), 256, 0, stream>>>(mb, nb, alpha);
  k_apply<<<dim3(16, 32), 256, 0, stream>>>(mb, nb, nT, alpha, g3, yb);
  k_gemm_bt<float><<<dim3(16, 32), 256, 0, stream>>>(yb, Wtb, out, C_DIM, C_DIM);
}

// Round 5
// 242.922 us; speedup vs baseline: 1.4978x; 1.4978x over previous
//
#include <hip/hip_runtime.h>
#include <stdint.h>

#define T_SEQ 2048
#define B_SZ 2
#define N_HEAD 16
#define D_HEAD 128
#define C_DIM 2048
#define M_ROWS (B_SZ*T_SEQ)   // 4096
#define N_BH (B_SZ*N_HEAD)    // 32

typedef _Float16 f16;
typedef f16 f16x8 __attribute__((ext_vector_type(8)));
typedef f16 f16x4 __attribute__((ext_vector_type(4)));
typedef float f32x4 __attribute__((ext_vector_type(4)));

#define MFMA_F16(a,b,c) __builtin_amdgcn_mfma_f32_16x16x32_f16(a,b,c,0,0,0)

#define BAR_LGKM() do { asm volatile("s_waitcnt lgkmcnt(0)" ::: "memory"); \
                        __builtin_amdgcn_s_barrier(); } while (0)
#define BAR_ALL()  do { asm volatile("s_waitcnt vmcnt(0) lgkmcnt(0)" ::: "memory"); \
                        __builtin_amdgcn_s_barrier(); } while (0)

// async global->LDS, 16B per lane; LDS dest is wave-uniform base + lane*16
__device__ __forceinline__ void gl_lds16(const void* g, void* l) {
  __builtin_amdgcn_global_load_lds(
      (const __attribute__((address_space(1))) unsigned int*)g,
      (__attribute__((address_space(3))) unsigned int*)l, 16, 0, 0);
}

// ---------------- prep: W -> Wb (fp16) and Wtb (fp16, transposed) ----------
__global__ void k_prep_w(const float* __restrict__ W, f16* __restrict__ Wb,
                         f16* __restrict__ Wtb) {
  __shared__ float tile[64][65];
  const int bx = blockIdx.x * 64;   // col base
  const int by = blockIdx.y * 64;   // row base
  const int t = threadIdx.x;
  const int tc = t & 63, tr4 = t >> 6;
  for (int rr = tr4; rr < 64; rr += 4) {
    float v = W[(size_t)(by + rr) * C_DIM + bx + tc];
    tile[rr][tc] = v;
    Wb[(size_t)(by + rr) * C_DIM + bx + tc] = (f16)v;
  }
  __syncthreads();
  for (int rr = tr4; rr < 64; rr += 4) {
    // Wtb[n][k] = W[k][n]
    Wtb[(size_t)(bx + rr) * C_DIM + by + tc] = (f16)tile[tc][rr];
  }
}

// ---------------- prep: x -> fp16 ------------------------------------------
__global__ void k_prep_x(const float* __restrict__ x, f16* __restrict__ xb) {
  int i = blockIdx.x * blockDim.x + threadIdx.x;
  const int stride = gridDim.x * blockDim.x;
  const int n4 = (M_ROWS * C_DIM) / 4;
  for (; i < n4; i += stride) {
    f32x4 v = ((const f32x4*)x)[i];
    f16x4 o; o[0]=(f16)v[0]; o[1]=(f16)v[1]; o[2]=(f16)v[2]; o[3]=(f16)v[3];
    ((f16x4*)xb)[i] = o;
  }
}

// ---------------- GEMM C[M][N] = sum_k A[m][k]*B[n][k]  (B^T layout) -------
template<typename OT>
__global__ __launch_bounds__(256, 2)
void k_gemm_bt(const f16* __restrict__ A, const f16* __restrict__ Bm,
               OT* __restrict__ C, int Nd, int Kd) {
  __shared__ __align__(16) f16 As[2][128 * 64];
  __shared__ __align__(16) f16 Bs[2][128 * 64];
  const int tid = threadIdx.x;
  const int lane = tid & 63, wid = tid >> 6;
  const int lr = lane & 15, lkg = lane >> 4;
  const int wr = wid >> 1, wc = wid & 1;
  const int tm = blockIdx.y * 128, tn = blockIdx.x * 128;

  f32x4 acc[4][4];
#pragma unroll
  for (int i = 0; i < 4; ++i)
#pragma unroll
    for (int j = 0; j < 4; ++j) acc[i][j] = (f32x4){0.f, 0.f, 0.f, 0.f};

  const int nkt = Kd >> 6;

  auto stage = [&](int buf, int kt) {
    const int k0 = kt << 6;
    for (int s = 0; s < 4; ++s) {
      const int r0 = (wid * 4 + s) * 8;
      const int r = r0 + (lane >> 3);
      const int lg = ((lane & 7) ^ (r & 7)) << 3;  // logical col (elems)
      gl_lds16(A + (size_t)(tm + r) * Kd + k0 + lg, &As[buf][r0 * 64]);
      gl_lds16(Bm + (size_t)(tn + r) * Kd + k0 + lg, &Bs[buf][r0 * 64]);
    }
  };

  stage(0, 0);
  int cur = 0;
  for (int kt = 0; kt < nkt; ++kt) {
    __syncthreads();                       // staged buf[cur] ready
    if (kt + 1 < nkt) stage(cur ^ 1, kt + 1);
#pragma unroll
    for (int kk = 0; kk < 2; ++kk) {
      f16x8 a[4], b[4];
#pragma unroll
      for (int i = 0; i < 4; ++i) {
        const int ra = wr * 64 + i * 16 + lr;
        const int ga = ((kk * 4 + lkg) ^ (ra & 7)) << 3;
        a[i] = *(const f16x8*)&As[cur][ra * 64 + ga];
        const int rb = wc * 64 + i * 16 + lr;
        const int gb = ((kk * 4 + lkg) ^ (rb & 7)) << 3;
        b[i] = *(const f16x8*)&Bs[cur][rb * 64 + gb];
      }
#pragma unroll
      for (int i = 0; i < 4; ++i)
#pragma unroll
        for (int j = 0; j < 4; ++j) acc[i][j] = MFMA_F16(a[i], b[j], acc[i][j]);
    }
    cur ^= 1;
  }
#pragma unroll
  for (int i = 0; i < 4; ++i) {
    const int row0 = tm + wr * 64 + i * 16 + lkg * 4;
#pragma unroll
    for (int j = 0; j < 4; ++j) {
      const int col = tn + wc * 64 + j * 16 + lr;
#pragma unroll
      for (int r = 0; r < 4; ++r)
        C[(size_t)(row0 + r) * Nd + col] = (OT)acc[i][j][r];
    }
  }
}

// ---------------- RMS norm: wb[B,T,H,D] -> n,m in [B,H,T,D] ---------------
__global__ __launch_bounds__(256, 4)
void k_rms(const f16* __restrict__ wb, const float* __restrict__ g1,
           const float* __restrict__ g2, f16* __restrict__ nb,
           f16* __restrict__ mb) {
  const int tid = threadIdx.x, lane = tid & 63, wid = tid >> 6;
  const int lr = lane & 15, grp = lane >> 4;
  float gs[8];
#pragma unroll
  for (int e = 0; e < 8; ++e)
    gs[e] = g1[lr * 8 + e] * g2[lr * 8 + e] * 0.08838834764831843f; // /sqrt(128)
  const int R = blockIdx.x * 16 + wid * 4 + grp;  // ((b*T+t)*H + h)
  const f16x8 w8 = *(const f16x8*)&wb[(size_t)R * 128 + lr * 8];
  float f[8];
  float ss = 0.f;
#pragma unroll
  for (int e = 0; e < 8; ++e) { f[e] = (float)w8[e]; ss += f[e] * f[e]; }
  ss += __shfl_xor(ss, 1); ss += __shfl_xor(ss, 2);
  ss += __shfl_xor(ss, 4); ss += __shfl_xor(ss, 8);
  const float scale = rsqrtf(ss * (1.f / 128.f) + 1.1920928955078125e-07f);
  const int hh = R & (N_HEAD - 1);
  const int bt = R >> 4;
  const int b = bt >> 11;
  const int t = bt & (T_SEQ - 1);
  const size_t dst = ((size_t)((b * N_HEAD + hh) * T_SEQ + t)) * 128 + lr * 8;
  f16x8 n8, m8;
#pragma unroll
  for (int e = 0; e < 8; ++e) {
    float nf = f[e] * scale;
    n8[e] = (f16)nf;
    m8[e] = (f16)(nf * gs[e]);
  }
  *(f16x8*)&nb[dst] = n8;
  *(f16x8*)&mb[dst] = m8;
}

// ---------------- transpose n[bh][t][d] -> nT[bh][d][t] --------------------
__global__ void k_tn(const f16* __restrict__ nin, f16* __restrict__ nT) {
  __shared__ __align__(16) f16 tile[64][72];
  const int t = threadIdx.x;
  const int c = t & 7, r4 = t >> 3;
  const int bh = blockIdx.z, t0 = blockIdx.x * 64, d0 = blockIdx.y * 64;
  const f16* src = nin + ((size_t)bh * T_SEQ + t0) * 128 + d0;
  for (int rr = r4; rr < 64; rr += 32)
    *(f16x8*)&tile[rr][c * 8] = *(const f16x8*)&src[(size_t)rr * 128 + c * 8];
  __syncthreads();
  f16* dst = nT + ((size_t)bh * 128 + d0) * T_SEQ + t0;
  for (int rr = r4; rr < 64; rr += 32) {
    f16x8 v;
#pragma unroll
    for (int e = 0; e < 8; ++e) v[e] = tile[c * 8 + e][rr];
    *(f16x8*)&dst[(size_t)rr * T_SEQ + c * 8] = v;
  }
}

// ---------------- stats v3: + XCD swizzle ----------------------------------
__global__ __launch_bounds__(256, 2)
void k_stats(const f16* __restrict__ mIn, const f16* __restrict__ nIn,
             float* __restrict__ alpha) {
  __shared__ __align__(16) f16 Ns[2][128 * 128];   // 64KB dbuf
  __shared__ float red[256];
  const int tid = threadIdx.x, lane = tid & 63, wid = tid >> 6;
  const int lr = lane & 15, lkg = lane >> 4;
  const int wr = wid >> 1, wc = wid & 1;
  // XCD swizzle: each XCD gets 4 consecutive bh (all 16 it) for L2 locality
  const int lin = blockIdx.x + (blockIdx.y << 4);
  const int swz = ((lin & 7) << 6) + (lin >> 3);
  const int it = swz & 15, bh = swz >> 4;
  const f16* mp = mIn + (size_t)bh * T_SEQ * 128;
  const f16* np = nIn + (size_t)bh * T_SEQ * 128;

  // A-operand fragments (M rows for this block), block-constant: 64 VGPR
  f16x8 msr[4][4];
#pragma unroll
  for (int i = 0; i < 4; ++i)
#pragma unroll
    for (int kk = 0; kk < 4; ++kk)
      msr[i][kk] = *(const f16x8*)&mp[(size_t)(it * 128 + wr * 64 + i * 16 + lr) * 128 +
                                      (kk * 4 + lkg) * 8];

  auto stageN = [&](int buf, int jt) {
#pragma unroll
    for (int s = 0; s < 8; ++s) {
      const int r0 = (wid * 8 + s) * 4;
      const int r = r0 + (lane >> 4);
      const int lg = ((lane & 15) ^ (r & 7)) << 3;
      gl_lds16(np + (size_t)(jt * 128 + r) * 128 + lg, &Ns[buf][r0 * 128]);
    }
  };

  float srun[16];
#pragma unroll
  for (int q = 0; q < 16; ++q) srun[q] = 0.f;

  stageN(0, 0);
  BAR_ALL();
  int cur = 0;
  for (int jt = 0; jt < 16; ++jt) {
    if (jt < 15) stageN(cur ^ 1, jt + 1);   // DMA overlaps QK+exp
    f32x4 acc[4][4];
#pragma unroll
    for (int i = 0; i < 4; ++i)
#pragma unroll
      for (int j = 0; j < 4; ++j) acc[i][j] = (f32x4){0.f, 0.f, 0.f, 0.f};
#pragma unroll
    for (int kk = 0; kk < 4; ++kk) {
      f16x8 b[4];
#pragma unroll
      for (int j = 0; j < 4; ++j) {
        const int rb = wc * 64 + j * 16 + lr;
        const int gb = ((kk * 4 + lkg) ^ (rb & 7)) << 3;
        b[j] = *(const f16x8*)&Ns[cur][rb * 128 + gb];
      }
#pragma unroll
      for (int i = 0; i < 4; ++i)
#pragma unroll
        for (int j = 0; j < 4; ++j)
          acc[i][j] = MFMA_F16(msr[i][kk], b[j], acc[i][j]);
    }
#pragma unroll
    for (int i = 0; i < 4; ++i)
#pragma unroll
      for (int r = 0; r < 4; ++r) {
        float s = __expf(acc[i][0][r]) + __expf(acc[i][1][r]) +
                  __expf(acc[i][2][r]) + __expf(acc[i][3][r]);
        srun[i * 4 + r] += s;
      }
    BAR_ALL();                  // staged Ns ready; all reads of cur done
    cur ^= 1;
  }
#pragma unroll
  for (int q = 0; q < 16; ++q) {
    float v = srun[q];
    v += __shfl_xor(v, 1); v += __shfl_xor(v, 2);
    v += __shfl_xor(v, 4); v += __shfl_xor(v, 8);
    srun[q] = v;
  }
  if (lr == 0) {
#pragma unroll
    for (int q = 0; q < 16; ++q) {
      const int row = wr * 64 + (q >> 2) * 16 + lkg * 4 + (q & 3);
      red[row * 2 + wc] = srun[q];
    }
  }
  __syncthreads();
  if (tid < 128) {
    const float s = red[tid * 2] + red[tid * 2 + 1];
    alpha[(size_t)bh * T_SEQ + it * 128 + tid] = 1.f / s;
  }
}

// ---------------- apply v5: msr in regs; Ns+Nts DMA dbuf; XCD swizzle ------
// LDS = Ns 32KB + Nts 32KB + Ps 16KB = 80KB; 2 barriers per j-step; all
// VMEM for step jt+1 issued at the TOP of step jt (full step of compute
// hides it before the end-of-step vmcnt(0) drain).
__global__ __launch_bounds__(256, 2)
void k_apply(const f16* __restrict__ mIn, const f16* __restrict__ nIn,
             const f16* __restrict__ nTIn, const float* __restrict__ alpha,
             const float* __restrict__ g3, f16* __restrict__ yb) {
  __shared__ __align__(16) f16 Ns[2][64 * 128];   // 32KB  j-rows, 128 d
  __shared__ __align__(16) f16 Nts[2][128 * 64];  // 32KB  d-rows, 64 j
  __shared__ __align__(16) f16 Ps[128 * 64];      // 16KB  i-rows, 64 j
  const int tid = threadIdx.x, lane = tid & 63, wid = tid >> 6;
  const int lr = lane & 15, lkg = lane >> 4;
  const int wj = wid >> 1;  // QK: j-half (32) | PV: d-half (64)
  const int wi = wid & 1;   // i-half (64) for both
  // XCD swizzle: each XCD gets 4 consecutive bh (all 16 it) for L2 locality
  const int lin = blockIdx.x + (blockIdx.y << 4);
  const int swz = ((lin & 7) << 6) + (lin >> 3);
  const int it = swz & 15, bh = swz >> 4;
  const int b = bh >> 4, hh = bh & 15;
  const f16* mp = mIn + (size_t)bh * T_SEQ * 128;
  const f16* np = nIn + (size_t)bh * T_SEQ * 128;
  const f16* ntp = nTIn + (size_t)bh * 128 * T_SEQ;
  const float* al = alpha + (size_t)bh * T_SEQ;

  // QK B-operand fragments (M rows for this block), block-constant: 64 VGPR
  f16x8 msr[4][4];
#pragma unroll
  for (int ii = 0; ii < 4; ++ii)
#pragma unroll
    for (int kk = 0; kk < 4; ++kk)
      msr[ii][kk] = *(const f16x8*)&mp[(size_t)(it * 128 + wi * 64 + ii * 16 + lr) * 128 +
                                       (kk * 4 + lkg) * 8];

  auto stageN = [&](int buf, int jt) {
#pragma unroll
    for (int s = 0; s < 4; ++s) {
      const int r0 = (wid * 4 + s) * 4;         // local j row (256B rows)
      const int r = r0 + (lane >> 4);
      const int lg = ((lane & 15) ^ (r & 7)) << 3;
      gl_lds16(np + (size_t)(jt * 64 + r) * 128 + lg, &Ns[buf][r0 * 128]);
    }
  };
  auto stageNT = [&](int buf, int jt) {
#pragma unroll
    for (int s = 0; s < 4; ++s) {
      const int r0 = (wid * 4 + s) * 8;         // d row (128B rows)
      const int r = r0 + (lane >> 3);
      const int lg = ((lane & 7) ^ (r & 7)) << 3;  // pre-swizzled source col
      gl_lds16(ntp + (size_t)r * T_SEQ + jt * 64 + lg, &Nts[buf][r0 * 64]);
    }
  };

  float ai[4];
#pragma unroll
  for (int ii = 0; ii < 4; ++ii) ai[ii] = al[it * 128 + wi * 64 + ii * 16 + lr];

  f32x4 yacc[4][4];
#pragma unroll
  for (int i = 0; i < 4; ++i)
#pragma unroll
    for (int j = 0; j < 4; ++j) yacc[i][j] = (f32x4){0.f, 0.f, 0.f, 0.f};

  stageN(0, 0);
  stageNT(0, 0);
  BAR_ALL();
  int cur = 0;
  for (int jt = 0; jt < 32; ++jt) {
    // aj loads FIRST (so their waitcnt doesn't force the DMA to drain early)
    float aj[8];
#pragma unroll
    for (int jj = 0; jj < 2; ++jj)
#pragma unroll
      for (int r = 0; r < 4; ++r)
        aj[jj * 4 + r] = al[jt * 64 + wj * 32 + jj * 16 + lkg * 4 + r];
    // issue ALL next-step VMEM at the top: full step of compute hides it
    if (jt < 31) { stageN(cur ^ 1, jt + 1); stageNT(cur ^ 1, jt + 1); }

    // ---- QK swapped: acc[j][i], A = Ns rows (LDS), B = msr (regs) ----
    f32x4 acc[2][4];
#pragma unroll
    for (int i = 0; i < 2; ++i)
#pragma unroll
      for (int j = 0; j < 4; ++j) acc[i][j] = (f32x4){0.f, 0.f, 0.f, 0.f};
#pragma unroll
    for (int kk = 0; kk < 4; ++kk) {
      f16x8 a[2];
#pragma unroll
      for (int jj = 0; jj < 2; ++jj) {
        const int jrow = wj * 32 + jj * 16 + lr;
        a[jj] = *(const f16x8*)&Ns[cur][jrow * 128 + (((kk * 4 + lkg) ^ (jrow & 7)) << 3)];
      }
#pragma unroll
      for (int jj = 0; jj < 2; ++jj)
#pragma unroll
        for (int ii = 0; ii < 4; ++ii)
          acc[jj][ii] = MFMA_F16(a[jj], msr[ii][kk], acc[jj][ii]);
    }

    // ---- P = exp(att)*(ai+aj) -> Ps[i][64 j], vectorized f16x4 ----
#pragma unroll
    for (int jj = 0; jj < 2; ++jj)
#pragma unroll
      for (int ii = 0; ii < 4; ++ii) {
        f16x4 o;
#pragma unroll
        for (int r = 0; r < 4; ++r) {
          const float p = __expf(acc[jj][ii][r]) * (ai[ii] + aj[jj * 4 + r]);
          o[r] = (f16)p;
        }
        const int il = wi * 64 + ii * 16 + lr;
        const int jl = wj * 32 + jj * 16 + lkg * 4;
        *(f16x4*)&Ps[il * 64 + (((jl >> 3) ^ (il & 7)) << 3) + (jl & 7)] = o;
      }
    BAR_LGKM();                    // Ps visible (prev PV reads already done)

    // ---- PV: yacc[d][i] += sum_j Nts[d][j] * Ps[i][j] ----
#pragma unroll
    for (int kk = 0; kk < 2; ++kk) {
      f16x8 a[4], bfr[4];
#pragma unroll
      for (int dd = 0; dd < 4; ++dd) {
        const int drow = wj * 64 + dd * 16 + lr;
        a[dd] = *(const f16x8*)&Nts[cur][drow * 64 + (((kk * 4 + lkg) ^ (drow & 7)) << 3)];
      }
#pragma unroll
      for (int ii = 0; ii < 4; ++ii) {
        const int irow = wi * 64 + ii * 16 + lr;
        bfr[ii] = *(const f16x8*)&Ps[irow * 64 + (((kk * 4 + lkg) ^ (irow & 7)) << 3)];
      }
#pragma unroll
      for (int dd = 0; dd < 4; ++dd)
#pragma unroll
        for (int ii = 0; ii < 4; ++ii)
          yacc[dd][ii] = MFMA_F16(a[dd], bfr[ii], yacc[dd][ii]);
    }
    BAR_ALL();                     // next Ns/Nts staged; Ps reads done
    cur ^= 1;
  }

  // ---- epilogue: yb[b, t=i, hh*128+d] = yacc * g3[d] ----
#pragma unroll
  for (int dd = 0; dd < 4; ++dd) {
    const int d0 = wj * 64 + dd * 16 + lkg * 4;
    float g3v[4];
#pragma unroll
    for (int r = 0; r < 4; ++r) g3v[r] = g3[d0 + r];
#pragma unroll
    for (int ii = 0; ii < 4; ++ii) {
      const int icol = wi * 64 + ii * 16 + lr;
      const size_t base =
          ((size_t)(b * T_SEQ + it * 128 + icol)) * C_DIM + hh * 128 + d0;
      f16x4 o;
#pragma unroll
      for (int r = 0; r < 4; ++r) o[r] = (f16)(yacc[dd][ii][r] * g3v[r]);
      *(f16x4*)&yb[base] = o;
    }
  }
}

// ---------------------------------------------------------------------------
extern "C" void kernel_launch(void* const* d_in, const int* in_sizes, int n_in,
                              void* d_out, int out_size, void* d_ws,
                              size_t ws_size, hipStream_t stream) {
  const float* x = (const float*)d_in[0];
  const float* W = (const float*)d_in[1];
  const float* g1 = (const float*)d_in[2];
  const float* g2 = (const float*)d_in[3];
  const float* g3 = (const float*)d_in[4];
  float* out = (float*)d_out;
  char* ws = (char*)d_ws;

  f16* xb   = (f16*)(ws);                      // 16,777,216 B
  f16* Wb   = (f16*)(ws + 16777216);           //  8,388,608
  f16* Wtb  = (f16*)(ws + 25165824);           //  8,388,608
  f16* wb   = (f16*)(ws + 33554432);           // 16,777,216
  f16* nb   = (f16*)(ws + 50331648);           // 16,777,216
  f16* mb   = (f16*)(ws + 67108864);           // 16,777,216
  f16* nT   = (f16*)(ws + 83886080);           // 16,777,216
  f16* yb   = (f16*)(ws + 100663296);          // 16,777,216
  float* alpha = (float*)(ws + 117440512);     //    262,144  (total ~112.3 MB)

  k_prep_w<<<dim3(32, 32), 256, 0, stream>>>(W, Wb, Wtb);
  k_prep_x<<<dim3(2048), 256, 0, stream>>>(x, xb);
  k_gemm_bt<f16><<<dim3(16, 32), 256, 0, stream>>>(xb, Wb, wb, C_DIM, C_DIM);
  k_rms<<<dim3(4096), 256, 0, stream>>>(wb, g1, g2, nb, mb);
  k_tn<<<dim3(32, 2, 32), 256, 0, stream>>>(nb, nT);
  k_stats<<<dim3(16, 32), 256, 0, stream>>>(mb, nb, alpha);
  k_apply<<<dim3(16, 32), 256, 0, stream>>>(mb, nb, nT, alpha, g3, yb);
  k_gemm_bt<float><<<dim3(16, 32), 256, 0, stream>>>(yb, Wtb, out, C_DIM, C_DIM);
}